// Round 3
// baseline (69.634 us; speedup 1.0000x reference)
//
#include <hip/hip_runtime.h>

typedef __attribute__((ext_vector_type(8))) __bf16 bf16x8;
typedef __attribute__((ext_vector_type(4))) float f32x4;

#define NB 16
#define CIN 64
#define CT 69
#define NO 128
#define HWSZ 1024
#define OUTC 133

// round-to-nearest-even fp32 -> bf16 pair packed into u32 (lo = first)
__device__ __forceinline__ unsigned pack_bf16(float a, float b) {
    unsigned ua = __float_as_uint(a);
    ua += 0x7fffu + ((ua >> 16) & 1u);
    unsigned ub = __float_as_uint(b);
    ub += 0x7fffu + ((ub >> 16) & 1u);
    return (ua >> 16) | (ub & 0xffff0000u);
}

__device__ __forceinline__ void gload16(const void* g, void* l) {
    __builtin_amdgcn_global_load_lds(
        (const __attribute__((address_space(1))) unsigned int*)g,
        (__attribute__((address_space(3))) unsigned int*)l, 16, 0, 0);
}

// ---------------------------------------------------------------------------
// Prep: blocks 0..511 xT, 512..527 wT, 528..607 passthrough channels.
// xT[b][h][ byte: w*128 + (ci*2 ^ ((w&7)<<4)) ] bf16 (swizzle baked into
// global layout, G21 both-sides-or-neither). wT[tap][ o*128 + swz(ci) ].
// ---------------------------------------------------------------------------
__global__ __launch_bounds__(256) void prep_kernel(
    const float* __restrict__ x, const float* __restrict__ cw,
    unsigned* __restrict__ xT, unsigned* __restrict__ wT,
    float* __restrict__ out)
{
    int blk = blockIdx.x;
    if (blk < 512) {
        int b = blk >> 5, h = blk & 31;
        int w = threadIdx.x & 31;
        int cp0 = threadIdx.x >> 5;
        const float* xr = x + (((size_t)b * CT) << 10) + h * 32 + w;
        unsigned* dst = xT + (size_t)blk * 1024 + w * 32;
        int sw = (w & 7) << 2;
#pragma unroll
        for (int r = 0; r < 4; ++r) {
            int cp = cp0 + r * 8;
            float v0 = xr[(size_t)(2 * cp) << 10];
            float v1 = xr[(size_t)(2 * cp + 1) << 10];
            dst[cp ^ sw] = pack_bf16(v0, v1);
        }
    } else if (blk < 528) {
        int tg = (blk - 512) * 256 + threadIdx.x;   // 0..4095
        int o = tg >> 5, cp = tg & 31;
        int sw = (o & 7) << 2;
#pragma unroll
        for (int tap = 0; tap < 9; ++tap) {
            float v0 = cw[((size_t)o * CIN + 2 * cp) * 9 + tap];
            float v1 = cw[((size_t)o * CIN + 2 * cp + 1) * 9 + tap];
            wT[tap * 4096 + o * 32 + (cp ^ sw)] = pack_bf16(v0, v1);
        }
    } else {
        int idx = (blk - 528) * 256 + threadIdx.x;  // 0..20479 quads
        int q = idx & 255;
        int c = (idx >> 8) % 5;
        int b = (idx >> 8) / 5;
        ((float4*)out)[((size_t)b * OUTC + NO + c) * 256 + q] =
            ((const float4*)x)[((size_t)b * CT + CIN + c) * 256 + q];
    }
}

// ---------------------------------------------------------------------------
// Fused conv (blocks 0..255) + sdw (blocks 256..319), 512 threads.
// Both emit per-block BN partial sums (sum, sumsq) per channel.
// ---------------------------------------------------------------------------
__global__ __launch_bounds__(512) void convsdw_kernel(
    const char* __restrict__ xT, const char* __restrict__ wT,
    const float* __restrict__ x, const float* __restrict__ sk,
    float* __restrict__ out, float* __restrict__ sdw,
    float* __restrict__ convpart, float* __restrict__ sdwpart)
{
    __shared__ __align__(16) char smem[49152];
    int tid = threadIdx.x;

    if (blockIdx.x < 256) {
        // =================== conv path ===================
        char* Xs = smem;
        char* W0 = smem + 16384;
        char* W1 = smem + 32768;

        int bid = blockIdx.x;
        int b = bid >> 4;
        int h0 = (bid & 15) * 2;

        int lane = tid & 63;
        int wid = tid >> 6;
        int lo = lane & 15, g = lane >> 4;
        int ks = wid >> 2;
        int mg = (wid >> 1) & 1;
        int ng = wid & 1;

#pragma unroll
        for (int q = 0; q < 2; ++q) {
            int ch = wid * 2 + q;
            int s = ch >> 2;
            int srch = h0 - 1 + s; srch = srch < 0 ? 0 : (srch > 31 ? 31 : srch);
            gload16(xT + ((size_t)(b * 32 + srch)) * 4096 + (ch & 3) * 1024 + lane * 16,
                    Xs + ch * 1024);
        }
#pragma unroll
        for (int q = 0; q < 2; ++q) {
            int ch = wid * 2 + q;
            gload16(wT + ch * 1024 + lane * 16, W0 + ch * 1024);
        }

        int acol[2][3];
#pragma unroll
        for (int i = 0; i < 2; ++i)
#pragma unroll
            for (int kj = 0; kj < 3; ++kj) {
                int cin = i * 16 + lo + kj - 1;
                cin = cin < 0 ? 0 : (cin > 31 ? 31 : cin);
                acol[i][kj] = cin * 128 + ((ks * 64 + g * 16) ^ ((cin & 7) << 4));
            }
        int boff[4];
#pragma unroll
        for (int n = 0; n < 4; ++n) {
            int o = ng * 64 + n * 16 + lo;
            boff[n] = o * 128 + ((ks * 64 + g * 16) ^ ((o & 7) << 4));
        }

        f32x4 acc[2][4];
#pragma unroll
        for (int i = 0; i < 2; ++i)
#pragma unroll
            for (int n = 0; n < 4; ++n) acc[i][n] = (f32x4){0.f, 0.f, 0.f, 0.f};

        __syncthreads();

#pragma unroll
        for (int tap = 0; tap < 9; ++tap) {
            int ki = tap / 3, kj = tap % 3;
            if (tap < 8) {
                char* wn = ((tap + 1) & 1) ? W1 : W0;
#pragma unroll
                for (int q = 0; q < 2; ++q) {
                    int ch = wid * 2 + q;
                    gload16(wT + (size_t)(tap + 1) * 16384 + ch * 1024 + lane * 16,
                            wn + ch * 1024);
                }
            }
            const char* wc = (tap & 1) ? W1 : W0;
            bf16x8 a0 = *(const bf16x8*)(Xs + (mg + ki) * 4096 + acol[0][kj]);
            bf16x8 a1 = *(const bf16x8*)(Xs + (mg + ki) * 4096 + acol[1][kj]);
#pragma unroll
            for (int n = 0; n < 4; ++n) {
                bf16x8 bv = *(const bf16x8*)(wc + boff[n]);
                acc[0][n] = __builtin_amdgcn_mfma_f32_16x16x32_bf16(a0, bv, acc[0][n], 0, 0, 0);
                acc[1][n] = __builtin_amdgcn_mfma_f32_16x16x32_bf16(a1, bv, acc[1][n], 0, 0, 0);
            }
            __syncthreads();
        }

        float* T = (float*)smem;   // [64][129]
        if (ks == 1) {
#pragma unroll
            for (int i = 0; i < 2; ++i)
#pragma unroll
                for (int n = 0; n < 4; ++n)
#pragma unroll
                    for (int r = 0; r < 4; ++r) {
                        int pixel = (mg * 2 + i) * 16 + g * 4 + r;
                        int o = ng * 64 + n * 16 + lo;
                        T[pixel * 129 + o] = acc[i][n][r];
                    }
        }
        __syncthreads();
        if (ks == 0) {
#pragma unroll
            for (int i = 0; i < 2; ++i)
#pragma unroll
                for (int n = 0; n < 4; ++n)
#pragma unroll
                    for (int r = 0; r < 4; ++r) {
                        int pixel = (mg * 2 + i) * 16 + g * 4 + r;
                        int o = ng * 64 + n * 16 + lo;
                        T[pixel * 129 + o] += acc[i][n][r];
                    }
        }
        __syncthreads();
        float* obase = out + (((size_t)b * OUTC) << 10) + h0 * 32;
#pragma unroll
        for (int r = 0; r < 4; ++r) {
            int o = r * 32 + (tid >> 4);
            int pq = tid & 15;
            float4 v;
            v.x = T[(pq * 4 + 0) * 129 + o];
            v.y = T[(pq * 4 + 1) * 129 + o];
            v.z = T[(pq * 4 + 2) * 129 + o];
            v.w = T[(pq * 4 + 3) * 129 + o];
            *(float4*)(obase + ((size_t)o << 10) + pq * 4) = v;
            // BN partials: 16 threads (pq) share this o; reduce their 64 px
            float s  = v.x + v.y + v.z + v.w;
            float s2 = v.x * v.x + v.y * v.y + v.z * v.z + v.w * v.w;
#pragma unroll
            for (int off = 1; off < 16; off <<= 1) {
                s  += __shfl_xor(s, off);
                s2 += __shfl_xor(s2, off);
            }
            if (pq == 0) {
                convpart[((size_t)o * 256 + bid) * 2]     = s;
                convpart[((size_t)o * 256 + bid) * 2 + 1] = s2;
            }
        }
    } else {
        // =================== sdw path ===================
        float* lsk = (float*)smem;   // 23040 B
        for (int i = tid; i < NO * 45; i += 512) lsk[i] = sk[i];
        __syncthreads();

        int bl = blockIdx.x - 256;       // 0..63
        int chalf = bl >> 5;
        int b = (bl >> 1) & 15;
        int hhalf = bl & 1;
        int r = tid >> 5, w = tid & 31;
        int h = hhalf * 16 + r;
        int hw = h * 32 + w;

        float win[45];
#pragma unroll
        for (int ch = 0; ch < 5; ++ch) {
            const float* xb = x + (((size_t)b * CT + CIN + ch) << 10);
#pragma unroll
            for (int ki = 0; ki < 3; ++ki) {
                int rr = h + ki - 1;
                rr = rr < 0 ? 0 : (rr > 31 ? 31 : rr);
                const float* rp = xb + (rr << 5);
#pragma unroll
                for (int kj = 0; kj < 3; ++kj) {
                    int cc = w + kj - 1;
                    cc = cc < 0 ? 0 : (cc > 31 ? 31 : cc);
                    win[ch * 9 + ki * 3 + kj] = rp[cc];
                }
            }
        }
#pragma unroll
        for (int ch = 0; ch < 2; ++ch) {
            float c = win[ch * 9 + 4];
#pragma unroll
            for (int k = 0; k < 9; ++k) win[ch * 9 + k] -= c;
        }

        int wid = tid >> 6;
        int wslot = (b * 2 + hhalf) * 8 + wid;    // 0..255 per ch
#pragma unroll 2
        for (int j = 0; j < 64; ++j) {
            int ch = chalf * 64 + j;
            const float* kk = &lsk[ch * 45];
            float s = 0.f;
#pragma unroll
            for (int q = 0; q < 45; ++q) s += fabsf(win[q] - kk[q]);
            sdw[(((size_t)b * NO + ch) << 10) + hw] = s;
            float ps = s, ps2 = s * s;
#pragma unroll
            for (int off = 32; off; off >>= 1) {
                ps  += __shfl_xor(ps, off);
                ps2 += __shfl_xor(ps2, off);
            }
            if ((tid & 63) == 0) {
                sdwpart[((size_t)ch * 256 + wslot) * 2]     = ps;
                sdwpart[((size_t)ch * 256 + wslot) * 2 + 1] = ps2;
            }
        }
    }
}

// ---------------------------------------------------------------------------
// Reduce: 256 blocks (conv ch 0..127, sdw ch 128..255) x 64 threads.
// Sums 256 partials/channel in fp64, writes mean + 1/sqrt(var+eps).
// ---------------------------------------------------------------------------
__global__ __launch_bounds__(64) void reduce_kernel(
    const float* __restrict__ convpart, const float* __restrict__ sdwpart,
    float* __restrict__ stats)
{
    int k = blockIdx.x, t = threadIdx.x;
    const float* part = (k < 128) ? convpart + (size_t)k * 512
                                  : sdwpart + (size_t)(k - 128) * 512;
    double s = 0.0, s2 = 0.0;
#pragma unroll
    for (int q = 0; q < 4; ++q) {
        s  += part[(t + q * 64) * 2];
        s2 += part[(t + q * 64) * 2 + 1];
    }
#pragma unroll
    for (int off = 32; off; off >>= 1) {
        s  += __shfl_down(s, off);
        s2 += __shfl_down(s2, off);
    }
    if (t == 0) {
        double n = 16384.0, m = s / n;
        double var = s2 / n - m * m;
        stats[k * 2]     = (float)m;
        stats[k * 2 + 1] = (float)(1.0 / sqrt(var + 1e-5));
    }
}

// ---------------------------------------------------------------------------
// Final: float4 out = relu(bn(conv) - relu(bn(sdw))), in-place on d_out.
// ---------------------------------------------------------------------------
__global__ __launch_bounds__(256) void final_kernel(
    const float* __restrict__ sdw, const float* __restrict__ stats,
    float* __restrict__ out)
{
    int idx = blockIdx.x * 256 + threadIdx.x;   // 0..524287 quads
    int q = idx & 255;
    int o = (idx >> 8) & 127;
    int b = idx >> 15;
    float4 cv = ((float4*)out)[((size_t)b * OUTC + o) * 256 + q];
    float4 sv = ((const float4*)sdw)[((size_t)b * NO + o) * 256 + q];
    float cm = stats[o * 2],       cs = stats[o * 2 + 1];
    float sm = stats[256 + o * 2], ss = stats[256 + o * 2 + 1];
    float4 rv;
    {
        float mu = (sv.x - sm) * ss; mu = mu > 0.f ? mu : 0.f;
        float v = (cv.x - cm) * cs - mu; rv.x = v > 0.f ? v : 0.f;
    }
    {
        float mu = (sv.y - sm) * ss; mu = mu > 0.f ? mu : 0.f;
        float v = (cv.y - cm) * cs - mu; rv.y = v > 0.f ? v : 0.f;
    }
    {
        float mu = (sv.z - sm) * ss; mu = mu > 0.f ? mu : 0.f;
        float v = (cv.z - cm) * cs - mu; rv.z = v > 0.f ? v : 0.f;
    }
    {
        float mu = (sv.w - sm) * ss; mu = mu > 0.f ? mu : 0.f;
        float v = (cv.w - cm) * cs - mu; rv.w = v > 0.f ? v : 0.f;
    }
    ((float4*)out)[((size_t)b * OUTC + o) * 256 + q] = rv;
}

extern "C" void kernel_launch(void* const* d_in, const int* in_sizes, int n_in,
                              void* d_out, int out_size, void* d_ws, size_t ws_size,
                              hipStream_t stream)
{
    const float* x  = (const float*)d_in[0];
    const float* cw = (const float*)d_in[1];
    const float* sk = (const float*)d_in[3];
    float* out = (float*)d_out;

    float*    sdw      = (float*)d_ws;                          // 8 MB
    float*    stats    = (float*)((char*)d_ws + 0x800000);      // 2 KB
    unsigned* xTu      = (unsigned*)((char*)d_ws + 0x810000);   // 2 MB
    unsigned* wTu      = (unsigned*)((char*)d_ws + 0xA10000);   // 144 KB
    float*    convpart = (float*)((char*)d_ws + 0xA40000);      // 256 KB
    float*    sdwpart  = (float*)((char*)d_ws + 0xA80000);      // 256 KB

    prep_kernel   <<<608, 256, 0, stream>>>(x, cw, xTu, wTu, out);
    convsdw_kernel<<<320, 512, 0, stream>>>((const char*)xTu, (const char*)wTu,
                                            x, sk, out, sdw, convpart, sdwpart);
    reduce_kernel <<<256, 64, 0, stream>>>(convpart, sdwpart, stats);
    final_kernel  <<<2048, 256, 0, stream>>>(sdw, stats, out);
}

// Round 4
// 43.492 us; speedup vs baseline: 1.6011x; 1.6011x over previous
//
#include <hip/hip_runtime.h>

typedef __attribute__((ext_vector_type(8))) __bf16 bf16x8;
typedef __attribute__((ext_vector_type(4))) float f32x4;

#define NB 16
#define CIN 64
#define CT 69
#define NO 128
#define HWSZ 1024
#define OUTC 133

// round-to-nearest-even fp32 -> bf16 pair packed into u32 (lo = first)
__device__ __forceinline__ unsigned pack_bf16(float a, float b) {
    unsigned ua = __float_as_uint(a);
    ua += 0x7fffu + ((ua >> 16) & 1u);
    unsigned ub = __float_as_uint(b);
    ub += 0x7fffu + ((ub >> 16) & 1u);
    return (ua >> 16) | (ub & 0xffff0000u);
}

__device__ __forceinline__ void gload16(const void* g, void* l) {
    __builtin_amdgcn_global_load_lds(
        (const __attribute__((address_space(1))) unsigned int*)g,
        (__attribute__((address_space(3))) unsigned int*)l, 16, 0, 0);
}

// ---------------------------------------------------------------------------
// Prep: blocks 0..511 xT, 512..527 wT, 528..607 passthrough channels.
// xT[b][h][ byte: w*128 + (ci*2 ^ ((w&7)<<4)) ] bf16 (swizzle baked into
// global layout, G21 both-sides-or-neither). wT[tap][ o*128 + swz(ci) ].
// ---------------------------------------------------------------------------
__global__ __launch_bounds__(256) void prep_kernel(
    const float* __restrict__ x, const float* __restrict__ cw,
    unsigned* __restrict__ xT, unsigned* __restrict__ wT,
    float* __restrict__ out)
{
    int blk = blockIdx.x;
    if (blk < 512) {
        int b = blk >> 5, h = blk & 31;
        int w = threadIdx.x & 31;
        int cp0 = threadIdx.x >> 5;
        const float* xr = x + (((size_t)b * CT) << 10) + h * 32 + w;
        unsigned* dst = xT + (size_t)blk * 1024 + w * 32;
        int sw = (w & 7) << 2;
#pragma unroll
        for (int r = 0; r < 4; ++r) {
            int cp = cp0 + r * 8;
            float v0 = xr[(size_t)(2 * cp) << 10];
            float v1 = xr[(size_t)(2 * cp + 1) << 10];
            dst[cp ^ sw] = pack_bf16(v0, v1);
        }
    } else if (blk < 528) {
        int tg = (blk - 512) * 256 + threadIdx.x;   // 0..4095
        int o = tg >> 5, cp = tg & 31;
        int sw = (o & 7) << 2;
#pragma unroll
        for (int tap = 0; tap < 9; ++tap) {
            float v0 = cw[((size_t)o * CIN + 2 * cp) * 9 + tap];
            float v1 = cw[((size_t)o * CIN + 2 * cp + 1) * 9 + tap];
            wT[tap * 4096 + o * 32 + (cp ^ sw)] = pack_bf16(v0, v1);
        }
    } else {
        int idx = (blk - 528) * 256 + threadIdx.x;  // 0..20479 quads
        int q = idx & 255;
        int c = (idx >> 8) % 5;
        int b = (idx >> 8) / 5;
        ((float4*)out)[((size_t)b * OUTC + NO + c) * 256 + q] =
            ((const float4*)x)[((size_t)b * CT + CIN + c) * 256 + q];
    }
}

// ---------------------------------------------------------------------------
// Conv as 9 accumulated MFMA GEMMs + BN-partials epilogue (proven r2/r3).
// 256 blocks x 512 threads.
// ---------------------------------------------------------------------------
__global__ __launch_bounds__(512) void conv_mfma_kernel(
    const char* __restrict__ xT, const char* __restrict__ wT,
    float* __restrict__ out, float* __restrict__ convpart)
{
    __shared__ __align__(16) char smem[49152];
    char* Xs = smem;
    char* W0 = smem + 16384;
    char* W1 = smem + 32768;

    int bid = blockIdx.x;
    int b = bid >> 4;
    int h0 = (bid & 15) * 2;

    int tid = threadIdx.x;
    int lane = tid & 63;
    int wid = tid >> 6;
    int lo = lane & 15, g = lane >> 4;
    int ks = wid >> 2;
    int mg = (wid >> 1) & 1;
    int ng = wid & 1;

#pragma unroll
    for (int q = 0; q < 2; ++q) {
        int ch = wid * 2 + q;
        int s = ch >> 2;
        int srch = h0 - 1 + s; srch = srch < 0 ? 0 : (srch > 31 ? 31 : srch);
        gload16(xT + ((size_t)(b * 32 + srch)) * 4096 + (ch & 3) * 1024 + lane * 16,
                Xs + ch * 1024);
    }
#pragma unroll
    for (int q = 0; q < 2; ++q) {
        int ch = wid * 2 + q;
        gload16(wT + ch * 1024 + lane * 16, W0 + ch * 1024);
    }

    int acol[2][3];
#pragma unroll
    for (int i = 0; i < 2; ++i)
#pragma unroll
        for (int kj = 0; kj < 3; ++kj) {
            int cin = i * 16 + lo + kj - 1;
            cin = cin < 0 ? 0 : (cin > 31 ? 31 : cin);
            acol[i][kj] = cin * 128 + ((ks * 64 + g * 16) ^ ((cin & 7) << 4));
        }
    int boff[4];
#pragma unroll
    for (int n = 0; n < 4; ++n) {
        int o = ng * 64 + n * 16 + lo;
        boff[n] = o * 128 + ((ks * 64 + g * 16) ^ ((o & 7) << 4));
    }

    f32x4 acc[2][4];
#pragma unroll
    for (int i = 0; i < 2; ++i)
#pragma unroll
        for (int n = 0; n < 4; ++n) acc[i][n] = (f32x4){0.f, 0.f, 0.f, 0.f};

    __syncthreads();

#pragma unroll
    for (int tap = 0; tap < 9; ++tap) {
        int ki = tap / 3, kj = tap % 3;
        if (tap < 8) {
            char* wn = ((tap + 1) & 1) ? W1 : W0;
#pragma unroll
            for (int q = 0; q < 2; ++q) {
                int ch = wid * 2 + q;
                gload16(wT + (size_t)(tap + 1) * 16384 + ch * 1024 + lane * 16,
                        wn + ch * 1024);
            }
        }
        const char* wc = (tap & 1) ? W1 : W0;
        bf16x8 a0 = *(const bf16x8*)(Xs + (mg + ki) * 4096 + acol[0][kj]);
        bf16x8 a1 = *(const bf16x8*)(Xs + (mg + ki) * 4096 + acol[1][kj]);
#pragma unroll
        for (int n = 0; n < 4; ++n) {
            bf16x8 bv = *(const bf16x8*)(wc + boff[n]);
            acc[0][n] = __builtin_amdgcn_mfma_f32_16x16x32_bf16(a0, bv, acc[0][n], 0, 0, 0);
            acc[1][n] = __builtin_amdgcn_mfma_f32_16x16x32_bf16(a1, bv, acc[1][n], 0, 0, 0);
        }
        __syncthreads();
    }

    float* T = (float*)smem;   // [64][129]
    if (ks == 1) {
#pragma unroll
        for (int i = 0; i < 2; ++i)
#pragma unroll
            for (int n = 0; n < 4; ++n)
#pragma unroll
                for (int r = 0; r < 4; ++r) {
                    int pixel = (mg * 2 + i) * 16 + g * 4 + r;
                    int o = ng * 64 + n * 16 + lo;
                    T[pixel * 129 + o] = acc[i][n][r];
                }
    }
    __syncthreads();
    if (ks == 0) {
#pragma unroll
        for (int i = 0; i < 2; ++i)
#pragma unroll
            for (int n = 0; n < 4; ++n)
#pragma unroll
                for (int r = 0; r < 4; ++r) {
                    int pixel = (mg * 2 + i) * 16 + g * 4 + r;
                    int o = ng * 64 + n * 16 + lo;
                    T[pixel * 129 + o] += acc[i][n][r];
                }
    }
    __syncthreads();
    float* obase = out + (((size_t)b * OUTC) << 10) + h0 * 32;
#pragma unroll
    for (int r = 0; r < 4; ++r) {
        int o = r * 32 + (tid >> 4);
        int pq = tid & 15;
        float4 v;
        v.x = T[(pq * 4 + 0) * 129 + o];
        v.y = T[(pq * 4 + 1) * 129 + o];
        v.z = T[(pq * 4 + 2) * 129 + o];
        v.w = T[(pq * 4 + 3) * 129 + o];
        *(float4*)(obase + ((size_t)o << 10) + pq * 4) = v;
        float s  = v.x + v.y + v.z + v.w;
        float s2 = v.x * v.x + v.y * v.y + v.z * v.z + v.w * v.w;
#pragma unroll
        for (int off = 1; off < 16; off <<= 1) {
            s  += __shfl_xor(s, off);
            s2 += __shfl_xor(s2, off);
        }
        if (pq == 0) {
            convpart[((size_t)o * 256 + bid) * 2]     = s;
            convpart[((size_t)o * 256 + bid) * 2 + 1] = s2;
        }
    }
}

// ---------------------------------------------------------------------------
// sdw: 512 blocks x 512 threads. Thread = 1 pixel, loops 8 channels.
// ch derived ONLY from blockIdx -> kk pointer is wave-uniform -> compiler
// scalarizes kk loads to s_load (inner loop = pure VALU, no LDS, no spill).
// Emits per-wave BN partials (256 slots/channel).
// ---------------------------------------------------------------------------
__global__ __launch_bounds__(512) void sdw_kernel(
    const float* __restrict__ x, const float* __restrict__ sk,
    float* __restrict__ sdw, float* __restrict__ sdwpart)
{
    int bl = blockIdx.x;            // 0..511
    int chg = bl >> 5;              // 0..15  (channel group of 8, uniform)
    int slice = bl & 31;            // 0..31  (512-pixel slice)
    int tid = threadIdx.x;
    int pix = slice * 512 + tid;    // 0..16383
    int b = pix >> 10;
    int hw = pix & 1023;
    int h = hw >> 5, w = hw & 31;

    float win[45];
#pragma unroll
    for (int ch = 0; ch < 5; ++ch) {
        const float* xb = x + (((size_t)b * CT + CIN + ch) << 10);
#pragma unroll
        for (int ki = 0; ki < 3; ++ki) {
            int rr = h + ki - 1;
            rr = rr < 0 ? 0 : (rr > 31 ? 31 : rr);
            const float* rp = xb + (rr << 5);
#pragma unroll
            for (int kj = 0; kj < 3; ++kj) {
                int cc = w + kj - 1;
                cc = cc < 0 ? 0 : (cc > 31 ? 31 : cc);
                win[ch * 9 + ki * 3 + kj] = rp[cc];
            }
        }
    }
#pragma unroll
    for (int ch = 0; ch < 2; ++ch) {
        float c = win[ch * 9 + 4];
#pragma unroll
        for (int k = 0; k < 9; ++k) win[ch * 9 + k] -= c;
    }

    int wid = tid >> 6;
    int wslot = slice * 8 + wid;    // 0..255 per channel
    for (int j = 0; j < 8; ++j) {
        int ch = chg * 8 + j;       // uniform across the block
        const float* kk = sk + (size_t)ch * 45;
        float s = 0.f;
#pragma unroll
        for (int q = 0; q < 45; ++q) s += fabsf(win[q] - kk[q]);
        sdw[(((size_t)b * NO + ch) << 10) + hw] = s;
        float ps = s, ps2 = s * s;
#pragma unroll
        for (int off = 32; off; off >>= 1) {
            ps  += __shfl_xor(ps, off);
            ps2 += __shfl_xor(ps2, off);
        }
        if ((tid & 63) == 0) {
            sdwpart[((size_t)ch * 256 + wslot) * 2]     = ps;
            sdwpart[((size_t)ch * 256 + wslot) * 2 + 1] = ps2;
        }
    }
}

// ---------------------------------------------------------------------------
// Reduce: 256 blocks (conv ch 0..127, sdw ch 128..255) x 64 threads.
// ---------------------------------------------------------------------------
__global__ __launch_bounds__(64) void reduce_kernel(
    const float* __restrict__ convpart, const float* __restrict__ sdwpart,
    float* __restrict__ stats)
{
    int k = blockIdx.x, t = threadIdx.x;
    const float* part = (k < 128) ? convpart + (size_t)k * 512
                                  : sdwpart + (size_t)(k - 128) * 512;
    double s = 0.0, s2 = 0.0;
#pragma unroll
    for (int q = 0; q < 4; ++q) {
        s  += part[(t + q * 64) * 2];
        s2 += part[(t + q * 64) * 2 + 1];
    }
#pragma unroll
    for (int off = 32; off; off >>= 1) {
        s  += __shfl_down(s, off);
        s2 += __shfl_down(s2, off);
    }
    if (t == 0) {
        double n = 16384.0, m = s / n;
        double var = s2 / n - m * m;
        stats[k * 2]     = (float)m;
        stats[k * 2 + 1] = (float)(1.0 / sqrt(var + 1e-5));
    }
}

// ---------------------------------------------------------------------------
// Final: float4 out = relu(bn(conv) - relu(bn(sdw))), in-place on d_out.
// ---------------------------------------------------------------------------
__global__ __launch_bounds__(256) void final_kernel(
    const float* __restrict__ sdw, const float* __restrict__ stats,
    float* __restrict__ out)
{
    int idx = blockIdx.x * 256 + threadIdx.x;   // 0..524287 quads
    int q = idx & 255;
    int o = (idx >> 8) & 127;
    int b = idx >> 15;
    float4 cv = ((float4*)out)[((size_t)b * OUTC + o) * 256 + q];
    float4 sv = ((const float4*)sdw)[((size_t)b * NO + o) * 256 + q];
    float cm = stats[o * 2],       cs = stats[o * 2 + 1];
    float sm = stats[256 + o * 2], ss = stats[256 + o * 2 + 1];
    float4 rv;
    {
        float mu = (sv.x - sm) * ss; mu = mu > 0.f ? mu : 0.f;
        float v = (cv.x - cm) * cs - mu; rv.x = v > 0.f ? v : 0.f;
    }
    {
        float mu = (sv.y - sm) * ss; mu = mu > 0.f ? mu : 0.f;
        float v = (cv.y - cm) * cs - mu; rv.y = v > 0.f ? v : 0.f;
    }
    {
        float mu = (sv.z - sm) * ss; mu = mu > 0.f ? mu : 0.f;
        float v = (cv.z - cm) * cs - mu; rv.z = v > 0.f ? v : 0.f;
    }
    {
        float mu = (sv.w - sm) * ss; mu = mu > 0.f ? mu : 0.f;
        float v = (cv.w - cm) * cs - mu; rv.w = v > 0.f ? v : 0.f;
    }
    ((float4*)out)[((size_t)b * OUTC + o) * 256 + q] = rv;
}

extern "C" void kernel_launch(void* const* d_in, const int* in_sizes, int n_in,
                              void* d_out, int out_size, void* d_ws, size_t ws_size,
                              hipStream_t stream)
{
    const float* x  = (const float*)d_in[0];
    const float* cw = (const float*)d_in[1];
    const float* sk = (const float*)d_in[3];
    float* out = (float*)d_out;

    float*    sdw      = (float*)d_ws;                          // 8 MB
    float*    stats    = (float*)((char*)d_ws + 0x800000);      // 2 KB
    unsigned* xTu      = (unsigned*)((char*)d_ws + 0x810000);   // 2 MB
    unsigned* wTu      = (unsigned*)((char*)d_ws + 0xA10000);   // 144 KB
    float*    convpart = (float*)((char*)d_ws + 0xA40000);      // 256 KB
    float*    sdwpart  = (float*)((char*)d_ws + 0xA80000);      // 256 KB

    prep_kernel    <<<608, 256, 0, stream>>>(x, cw, xTu, wTu, out);
    conv_mfma_kernel<<<256, 512, 0, stream>>>((const char*)xTu, (const char*)wTu,
                                              out, convpart);
    sdw_kernel     <<<512, 512, 0, stream>>>(x, sk, sdw, sdwpart);
    reduce_kernel  <<<256, 64, 0, stream>>>(convpart, sdwpart, stats);
    final_kernel   <<<2048, 256, 0, stream>>>(sdw, stats, out);
}